// Round 2
// baseline (378.071 us; speedup 1.0000x reference)
//
#include <hip/hip_runtime.h>
#include <hip/hip_bf16.h>
#include <cstdint>

typedef unsigned short u16;
typedef unsigned int   u32;

typedef __attribute__((ext_vector_type(8))) short short8;   // 8 x bf16 (4 VGPRs)
typedef __attribute__((ext_vector_type(4))) float f32x4;    // MFMA accumulator

__device__ __forceinline__ float b2f(u16 v) { return __uint_as_float(((u32)v) << 16); }
__device__ __forceinline__ u16 f2b(float f) {
    u32 u = __float_as_uint(f);
    u += 0x7FFFu + ((u >> 16) & 1u);   // round-to-nearest-even
    return (u16)(u >> 16);
}

#define G2L16(gp, lp) __builtin_amdgcn_global_load_lds(                       \
    (const __attribute__((address_space(1))) void*)(gp),                      \
    (__attribute__((address_space(3))) void*)(lp), 16, 0, 0)

// ---------------------------------------------------------------------------
// Causal cumulative mean of iV (f32 in) -> avg (bf16 out).
// S=2048 in 32 chunks of 64. Pass 1: per-chunk sums (f32). Pass 2: prefix+scan.
// ---------------------------------------------------------------------------
__global__ void chunk_sum_kernel(const float* __restrict__ iV, float* __restrict__ csum,
                                 int S, int D) {
    const int c = blockIdx.x & 31;
    const int b = blockIdx.x >> 5;
    const float* base = iV + ((size_t)b * S + (size_t)c * 64) * D;
    for (int d = threadIdx.x; d < D; d += 256) {
        float s = 0.f;
        #pragma unroll 8
        for (int i = 0; i < 64; ++i) s += base[(size_t)i * D + d];
        csum[((size_t)b * 32 + c) * D + d] = s;
    }
}

__global__ void scan_kernel(const float* __restrict__ iV, const float* __restrict__ csum,
                            u16* __restrict__ avg, int S, int D) {
    const int c = blockIdx.x & 31;
    const int b = blockIdx.x >> 5;
    const size_t off = ((size_t)b * S + (size_t)c * 64) * D;
    for (int d = threadIdx.x; d < D; d += 256) {
        float acc = 0.f;
        for (int cc = 0; cc < c; ++cc) acc += csum[((size_t)b * 32 + cc) * D + d];
        const float* src = iV + off + d;
        u16*         dst = avg + off + d;
        const int s0 = c * 64;
        #pragma unroll 8
        for (int i = 0; i < 64; ++i) {
            acc += src[(size_t)i * D];
            dst[(size_t)i * D] = f2b(acc / (float)(s0 + i + 1));
        }
    }
}

// ---------------------------------------------------------------------------
// Transpose f32 (R x C) -> bf16 (C x R)
// ---------------------------------------------------------------------------
__global__ void transpose_f32_bf16(const float* __restrict__ in, u16* __restrict__ out,
                                   int R, int C) {
    __shared__ float tile[32][33];
    const int bx = blockIdx.x * 32;
    const int by = blockIdx.y * 32;
    const int tx = threadIdx.x, ty = threadIdx.y;
    #pragma unroll
    for (int i = 0; i < 32; i += 8)
        tile[ty + i][tx] = in[(size_t)(by + ty + i) * C + (bx + tx)];
    __syncthreads();
    #pragma unroll
    for (int i = 0; i < 32; i += 8)
        out[(size_t)(bx + ty + i) * R + (by + tx)] = f2b(tile[tx][ty + i]);
}

// ---------------------------------------------------------------------------
// Cast f32 -> bf16, 4 elements per thread
// ---------------------------------------------------------------------------
__global__ void cast_bf16_kernel(const float* __restrict__ in, u16* __restrict__ out, int n4) {
    int i = blockIdx.x * blockDim.x + threadIdx.x;
    if (i >= n4) return;
    const float4 v = *(const float4*)(in + (size_t)i * 4);
    ushort4 o;
    o.x = f2b(v.x); o.y = f2b(v.y); o.z = f2b(v.z); o.w = f2b(v.w);
    *(ushort4*)(out + (size_t)i * 4) = o;
}

// ---------------------------------------------------------------------------
// MFMA GEMM: C = epilogue(A @ Bt^T + bias). A: M x K bf16 row-major.
// Bt: N x K bf16 (pre-transposed weight). 128x128 tile, BK=32, 4 waves,
// 4x4 16x16x32 frags/wave. EPI: 0 = relu(x+b), 1 = x+b.  Bias f32, out bf16.
// ---------------------------------------------------------------------------
template <int EPI>
__global__ __launch_bounds__(256, 2)
void gemm_kernel(const u16* __restrict__ A, const u16* __restrict__ Bt,
                 const float* __restrict__ bias, u16* __restrict__ C,
                 int M, int N, int K) {
    __shared__ u16 As[128 * 32];
    __shared__ u16 Bs[128 * 32];

    const int tid  = threadIdx.x;
    const int m0   = blockIdx.x * 128;
    const int n0   = blockIdx.y * 128;
    const int wave = tid >> 6, lane = tid & 63;
    const int wm   = (wave & 1) << 6;
    const int wn   = (wave >> 1) << 6;
    const int quad = lane >> 4, l16 = lane & 15;

    f32x4 acc[4][4];
    #pragma unroll
    for (int i = 0; i < 4; ++i)
        #pragma unroll
        for (int j = 0; j < 4; ++j) acc[i][j] = (f32x4){0.f, 0.f, 0.f, 0.f};

    const int o1 = tid * 16, o2 = o1 + 4096;
    const int r1 = o1 >> 6, c1 = o1 & 63;
    const int r2 = o2 >> 6, c2 = o2 & 63;

    const int ktiles = K >> 5;
    for (int kt = 0; kt < ktiles; ++kt) {
        const int kb = kt << 5;
        const char* Ab = (const char*)(A + kb);
        const char* Bb = (const char*)(Bt + kb);
        G2L16(Ab + (size_t)(m0 + r1) * K * 2 + c1, (char*)As + o1);
        G2L16(Ab + (size_t)(m0 + r2) * K * 2 + c2, (char*)As + o2);
        G2L16(Bb + (size_t)(n0 + r1) * K * 2 + c1, (char*)Bs + o1);
        G2L16(Bb + (size_t)(n0 + r2) * K * 2 + c2, (char*)Bs + o2);
        __syncthreads();

        short8 af[4], bf[4];
        #pragma unroll
        for (int mi = 0; mi < 4; ++mi)
            af[mi] = *(const short8*)(As + (wm + mi * 16 + l16) * 32 + quad * 8);
        #pragma unroll
        for (int ni = 0; ni < 4; ++ni)
            bf[ni] = *(const short8*)(Bs + (wn + ni * 16 + l16) * 32 + quad * 8);
        #pragma unroll
        for (int mi = 0; mi < 4; ++mi)
            #pragma unroll
            for (int ni = 0; ni < 4; ++ni)
                acc[mi][ni] = __builtin_amdgcn_mfma_f32_16x16x32_bf16(
                    af[mi], bf[ni], acc[mi][ni], 0, 0, 0);
        __syncthreads();
    }

    #pragma unroll
    for (int ni = 0; ni < 4; ++ni) {
        const int col = n0 + wn + ni * 16 + l16;
        const float bv = bias[col];
        #pragma unroll
        for (int mi = 0; mi < 4; ++mi) {
            const int row0 = m0 + wm + mi * 16 + quad * 4;
            #pragma unroll
            for (int r = 0; r < 4; ++r) {
                float v = acc[mi][ni][r] + bv;
                if (EPI == 0) v = fmaxf(v, 0.f);
                C[(size_t)(row0 + r) * N + col] = f2b(v);
            }
        }
    }
}

// ---------------------------------------------------------------------------
// Fused GEMM3 + sigmoid + gate.
// For out-cols [n0, n0+128): gi = sigmoid(concat(iQ,ffn) @ Wg[:,col] + bg[col]),
// gf = same at col+1024.  out = gi*iQ + gf*ffn  (f32 out).
// A is split: k<1024 -> iQb (bf16 cast of iQ), k>=1024 -> ffn (bf16).
// Two B tiles per block: Wgt rows [n0,n0+128) and [n0+1024, n0+1152).
// ---------------------------------------------------------------------------
__global__ __launch_bounds__(256, 2)
void gemm_gate_kernel(const u16* __restrict__ iQb, const u16* __restrict__ ffn,
                      const u16* __restrict__ Wgt, const float* __restrict__ bg,
                      const float* __restrict__ iQ, float* __restrict__ out,
                      int M, int D2 /*2048*/) {
    __shared__ u16 As [128 * 32];
    __shared__ u16 Bs0[128 * 32];
    __shared__ u16 Bs1[128 * 32];

    const int tid  = threadIdx.x;
    const int m0   = blockIdx.x * 128;
    const int n0   = blockIdx.y * 128;          // out-col tile, n0 < 1024
    const int wave = tid >> 6, lane = tid & 63;
    const int wm   = (wave & 1) << 6;
    const int wn   = (wave >> 1) << 6;
    const int quad = lane >> 4, l16 = lane & 15;
    const int D = D2 >> 1;                      // 1024

    f32x4 acc[2][4][4];
    #pragma unroll
    for (int p = 0; p < 2; ++p)
        #pragma unroll
        for (int i = 0; i < 4; ++i)
            #pragma unroll
            for (int j = 0; j < 4; ++j) acc[p][i][j] = (f32x4){0.f, 0.f, 0.f, 0.f};

    const int o1 = tid * 16, o2 = o1 + 4096;
    const int r1 = o1 >> 6, c1 = o1 & 63;
    const int r2 = o2 >> 6, c2 = o2 & 63;

    const int ktiles = D2 >> 5;                 // 64
    for (int kt = 0; kt < ktiles; ++kt) {
        const int kb = kt << 5;
        const char* Ab = (const char*)((kb < D) ? (iQb + kb) : (ffn + (kb - D)));
        const char* B0 = (const char*)(Wgt + (size_t)n0 * D2 + kb);
        const char* B1 = (const char*)(Wgt + (size_t)(n0 + D) * D2 + kb);
        G2L16(Ab + (size_t)(m0 + r1) * D * 2 + c1, (char*)As + o1);
        G2L16(Ab + (size_t)(m0 + r2) * D * 2 + c2, (char*)As + o2);
        G2L16(B0 + (size_t)r1 * D2 * 2 + c1, (char*)Bs0 + o1);
        G2L16(B0 + (size_t)r2 * D2 * 2 + c2, (char*)Bs0 + o2);
        G2L16(B1 + (size_t)r1 * D2 * 2 + c1, (char*)Bs1 + o1);
        G2L16(B1 + (size_t)r2 * D2 * 2 + c2, (char*)Bs1 + o2);
        __syncthreads();

        short8 af[4], bf0[4], bf1[4];
        #pragma unroll
        for (int mi = 0; mi < 4; ++mi)
            af[mi] = *(const short8*)(As + (wm + mi * 16 + l16) * 32 + quad * 8);
        #pragma unroll
        for (int ni = 0; ni < 4; ++ni) {
            bf0[ni] = *(const short8*)(Bs0 + (wn + ni * 16 + l16) * 32 + quad * 8);
            bf1[ni] = *(const short8*)(Bs1 + (wn + ni * 16 + l16) * 32 + quad * 8);
        }
        #pragma unroll
        for (int mi = 0; mi < 4; ++mi)
            #pragma unroll
            for (int ni = 0; ni < 4; ++ni) {
                acc[0][mi][ni] = __builtin_amdgcn_mfma_f32_16x16x32_bf16(
                    af[mi], bf0[ni], acc[0][mi][ni], 0, 0, 0);
                acc[1][mi][ni] = __builtin_amdgcn_mfma_f32_16x16x32_bf16(
                    af[mi], bf1[ni], acc[1][mi][ni], 0, 0, 0);
            }
        __syncthreads();
    }

    #pragma unroll
    for (int ni = 0; ni < 4; ++ni) {
        const int col = n0 + wn + ni * 16 + l16;
        const float bgi = bg[col];
        const float bgf = bg[col + D];
        #pragma unroll
        for (int mi = 0; mi < 4; ++mi) {
            const int row0 = m0 + wm + mi * 16 + quad * 4;
            #pragma unroll
            for (int r = 0; r < 4; ++r) {
                const size_t idx = (size_t)(row0 + r) * D + col;
                const float gi = 1.0f / (1.0f + __expf(-(acc[0][mi][ni][r] + bgi)));
                const float gf = 1.0f / (1.0f + __expf(-(acc[1][mi][ni][r] + bgf)));
                out[idx] = gi * iQ[idx] + gf * b2f(ffn[idx]);
            }
        }
    }
}

// ---------------------------------------------------------------------------
extern "C" void kernel_launch(void* const* d_in, const int* in_sizes, int n_in,
                              void* d_out, int out_size, void* d_ws, size_t ws_size,
                              hipStream_t stream) {
    const int B = 4, S = 2048, D = 1024, D2 = 2048;
    const int M = B * S;  // 8192

    const float* iQ = (const float*)d_in[0];
    const float* iV = (const float*)d_in[1];
    const float* W1 = (const float*)d_in[2];
    const float* b1 = (const float*)d_in[3];
    const float* W2 = (const float*)d_in[4];
    const float* b2 = (const float*)d_in[5];
    const float* Wg = (const float*)d_in[6];
    const float* bg = (const float*)d_in[7];
    float* out = (float*)d_out;

    // workspace (40 MB total), regions overlaid by lifetime:
    //  region A (16MB): avg  -> (after gemm1) ffn
    //  region B (16MB): csum -> h -> (after gemm2) iQb
    //  region D ( 8MB): W1t -> W2t -> Wgt
    u16* regA = (u16*)d_ws;                       // M*D bf16
    u16* regB = regA + (size_t)M * D;             // M*D bf16
    u16* regD = regB + (size_t)M * D;             // D2*D2 bf16 (8MB)

    u16*   avg  = regA;
    u16*   ffn  = regA;
    float* csum = (float*)regB;                   // B*32*D f32 (512KB)
    u16*   h    = regB;
    u16*   iQb  = regB;
    u16*   W1t  = regD;
    u16*   W2t  = regD;
    u16*   Wgt  = regD;

    dim3 tb(32, 8);
    // stage 0: W1 transpose + cumulative mean
    transpose_f32_bf16<<<dim3(D / 32, D / 32), tb, 0, stream>>>(W1, W1t, D, D);
    chunk_sum_kernel<<<B * 32, 256, 0, stream>>>(iV, csum, S, D);
    scan_kernel<<<B * 32, 256, 0, stream>>>(iV, csum, avg, S, D);

    // gemm1: h = relu(avg @ W1 + b1)   (writes over csum region — csum dead)
    gemm_kernel<0><<<dim3(M / 128, D / 128), 256, 0, stream>>>(avg, W1t, b1, h, M, D, D);

    // gemm2: ffn = h @ W2 + b2   (ffn overlays avg — avg dead)
    transpose_f32_bf16<<<dim3(D / 32, D / 32), tb, 0, stream>>>(W2, W2t, D, D);
    gemm_kernel<1><<<dim3(M / 128, D / 128), 256, 0, stream>>>(h, W2t, b2, ffn, M, D, D);

    // gemm3 fused with sigmoid+gate: out = gi*iQ + gf*ffn   (iQb overlays h — h dead)
    cast_bf16_kernel<<<(M * D / 4 + 255) / 256, 256, 0, stream>>>(iQ, iQb, M * D / 4);
    transpose_f32_bf16<<<dim3(D2 / 32, D2 / 32), tb, 0, stream>>>(Wg, Wgt, D2, D2);
    gemm_gate_kernel<<<dim3(M / 128, D / 128), 256, 0, stream>>>(
        iQb, ffn, Wgt, bg, iQ, out, M, D2);
}

// Round 3
// 304.313 us; speedup vs baseline: 1.2424x; 1.2424x over previous
//
#include <hip/hip_runtime.h>
#include <hip/hip_bf16.h>
#include <cstdint>

typedef unsigned short u16;
typedef unsigned int   u32;

typedef __attribute__((ext_vector_type(8))) short short8;   // 8 x bf16 (4 VGPRs)
typedef __attribute__((ext_vector_type(4))) float f32x4;    // MFMA accumulator

__device__ __forceinline__ float b2f(u16 v) { return __uint_as_float(((u32)v) << 16); }
__device__ __forceinline__ u16 f2b(float f) {
    u32 u = __float_as_uint(f);
    u += 0x7FFFu + ((u >> 16) & 1u);   // round-to-nearest-even
    return (u16)(u >> 16);
}

#define G2L16(gp, lp) __builtin_amdgcn_global_load_lds(                       \
    (const __attribute__((address_space(1))) void*)(gp),                      \
    (__attribute__((address_space(3))) void*)(lp), 16, 0, 0)

// ---------------------------------------------------------------------------
// Fused prologue (all independent work, one dispatch):
//   blocks [0,1024)      : W1 (1024x1024 f32) -> W1t (bf16, transposed)
//   blocks [1024,2048)   : W2 -> W2t
//   blocks [2048,6144)   : Wg (2048x2048) -> Wgt
//   blocks [6144,14336)  : cast iQ f32 -> iQb bf16
//   blocks [14336,14592) : chunk sums of iV (64 chunks of 32 rows per batch)
// ---------------------------------------------------------------------------
__device__ __forceinline__ void transpose_body(const float* __restrict__ in,
                                               u16* __restrict__ out,
                                               int R, int C, int lb, int tilesX,
                                               float (*tile)[33]) {
    const int bx = (lb % tilesX) * 32;
    const int by = (lb / tilesX) * 32;
    const int tx = threadIdx.x & 31, ty = threadIdx.x >> 5;   // 32 x 8
    #pragma unroll
    for (int i = 0; i < 32; i += 8)
        tile[ty + i][tx] = in[(size_t)(by + ty + i) * C + (bx + tx)];
    __syncthreads();
    #pragma unroll
    for (int i = 0; i < 32; i += 8)
        out[(size_t)(bx + ty + i) * R + (by + tx)] = f2b(tile[tx][ty + i]);
}

__global__ void prologue_kernel(const float* __restrict__ W1, u16* __restrict__ W1t,
                                const float* __restrict__ W2, u16* __restrict__ W2t,
                                const float* __restrict__ Wg, u16* __restrict__ Wgt,
                                const float* __restrict__ iQ, u16* __restrict__ iQb,
                                const float* __restrict__ iV, float* __restrict__ csum) {
    __shared__ float tile[32][33];
    const int bid = blockIdx.x;
    const int tid = threadIdx.x;
    if (bid < 1024) {
        transpose_body(W1, W1t, 1024, 1024, bid, 32, tile);
    } else if (bid < 2048) {
        transpose_body(W2, W2t, 1024, 1024, bid - 1024, 32, tile);
    } else if (bid < 6144) {
        transpose_body(Wg, Wgt, 2048, 2048, bid - 2048, 64, tile);
    } else if (bid < 14336) {
        const size_t i = ((size_t)(bid - 6144) * 256 + tid) * 4;
        const float4 v = *(const float4*)(iQ + i);
        ushort4 o;
        o.x = f2b(v.x); o.y = f2b(v.y); o.z = f2b(v.z); o.w = f2b(v.w);
        *(ushort4*)(iQb + i) = o;
    } else {
        // chunk sums: 32-row chunks, 64 chunks per batch, 4 batches -> 256 blocks
        const int idx = bid - 14336;
        const int b = idx >> 6, c = idx & 63;
        const int d = tid * 4;                              // D = 1024
        const float* src = iV + ((size_t)(b * 2048 + c * 32)) * 1024 + d;
        float4 s = {0.f, 0.f, 0.f, 0.f};
        #pragma unroll 8
        for (int i = 0; i < 32; ++i) {
            const float4 v = *(const float4*)(src + (size_t)i * 1024);
            s.x += v.x; s.y += v.y; s.z += v.z; s.w += v.w;
        }
        *(float4*)(csum + ((size_t)(b * 64 + c)) * 1024 + d) = s;
    }
}

// ---------------------------------------------------------------------------
// Scan: prefix over chunk sums + in-chunk serial scan -> avg (bf16). 256 blocks.
// ---------------------------------------------------------------------------
__global__ void scan_kernel(const float* __restrict__ iV, const float* __restrict__ csum,
                            u16* __restrict__ avg) {
    const int c = blockIdx.x & 63, b = blockIdx.x >> 6;
    const int d = threadIdx.x * 4;
    float4 acc = {0.f, 0.f, 0.f, 0.f};
    const float* cs = csum + (size_t)b * 64 * 1024 + d;
    for (int cc = 0; cc < c; ++cc) {
        const float4 v = *(const float4*)(cs + (size_t)cc * 1024);
        acc.x += v.x; acc.y += v.y; acc.z += v.z; acc.w += v.w;
    }
    const size_t off = ((size_t)(b * 2048 + c * 32)) * 1024 + d;
    const float* src = iV + off;
    u16*         dst = avg + off;
    const int s0 = c * 32;
    #pragma unroll 4
    for (int i = 0; i < 32; ++i) {
        const float4 v = *(const float4*)(src + (size_t)i * 1024);
        acc.x += v.x; acc.y += v.y; acc.z += v.z; acc.w += v.w;
        const float inv = 1.0f / (float)(s0 + i + 1);
        ushort4 o;
        o.x = f2b(acc.x * inv); o.y = f2b(acc.y * inv);
        o.z = f2b(acc.z * inv); o.w = f2b(acc.w * inv);
        *(ushort4*)(dst + (size_t)i * 1024) = o;
    }
}

// ---------------------------------------------------------------------------
// MFMA GEMM: C = epilogue(A @ Bt^T + bias). A: M x K bf16 row-major.
// Bt: N x K bf16 (pre-transposed weight). 128x128 tile, BK=32, 4 waves,
// 4x4 16x16x32 frags/wave. EPI: 0 = relu(x+b), 1 = x+b.  Bias f32, out bf16.
// ---------------------------------------------------------------------------
template <int EPI>
__global__ __launch_bounds__(256, 2)
void gemm_kernel(const u16* __restrict__ A, const u16* __restrict__ Bt,
                 const float* __restrict__ bias, u16* __restrict__ C,
                 int M, int N, int K) {
    __shared__ u16 As[128 * 32];
    __shared__ u16 Bs[128 * 32];

    const int tid  = threadIdx.x;
    const int m0   = blockIdx.x * 128;
    const int n0   = blockIdx.y * 128;
    const int wave = tid >> 6, lane = tid & 63;
    const int wm   = (wave & 1) << 6;
    const int wn   = (wave >> 1) << 6;
    const int quad = lane >> 4, l16 = lane & 15;

    f32x4 acc[4][4];
    #pragma unroll
    for (int i = 0; i < 4; ++i)
        #pragma unroll
        for (int j = 0; j < 4; ++j) acc[i][j] = (f32x4){0.f, 0.f, 0.f, 0.f};

    const int o1 = tid * 16, o2 = o1 + 4096;
    const int r1 = o1 >> 6, c1 = o1 & 63;
    const int r2 = o2 >> 6, c2 = o2 & 63;

    const int ktiles = K >> 5;
    for (int kt = 0; kt < ktiles; ++kt) {
        const int kb = kt << 5;
        const char* Ab = (const char*)(A + kb);
        const char* Bb = (const char*)(Bt + kb);
        G2L16(Ab + (size_t)(m0 + r1) * K * 2 + c1, (char*)As + o1);
        G2L16(Ab + (size_t)(m0 + r2) * K * 2 + c2, (char*)As + o2);
        G2L16(Bb + (size_t)(n0 + r1) * K * 2 + c1, (char*)Bs + o1);
        G2L16(Bb + (size_t)(n0 + r2) * K * 2 + c2, (char*)Bs + o2);
        __syncthreads();

        short8 af[4], bf[4];
        #pragma unroll
        for (int mi = 0; mi < 4; ++mi)
            af[mi] = *(const short8*)(As + (wm + mi * 16 + l16) * 32 + quad * 8);
        #pragma unroll
        for (int ni = 0; ni < 4; ++ni)
            bf[ni] = *(const short8*)(Bs + (wn + ni * 16 + l16) * 32 + quad * 8);
        #pragma unroll
        for (int mi = 0; mi < 4; ++mi)
            #pragma unroll
            for (int ni = 0; ni < 4; ++ni)
                acc[mi][ni] = __builtin_amdgcn_mfma_f32_16x16x32_bf16(
                    af[mi], bf[ni], acc[mi][ni], 0, 0, 0);
        __syncthreads();
    }

    #pragma unroll
    for (int ni = 0; ni < 4; ++ni) {
        const int col = n0 + wn + ni * 16 + l16;
        const float bv = bias[col];
        #pragma unroll
        for (int mi = 0; mi < 4; ++mi) {
            const int row0 = m0 + wm + mi * 16 + quad * 4;
            #pragma unroll
            for (int r = 0; r < 4; ++r) {
                float v = acc[mi][ni][r] + bv;
                if (EPI == 0) v = fmaxf(v, 0.f);
                C[(size_t)(row0 + r) * N + col] = f2b(v);
            }
        }
    }
}

// ---------------------------------------------------------------------------
// Fused GEMM3 + sigmoid + gate.  out = gi*iQ + gf*ffn  (f32 out), where
// gi/gf = sigmoid(concat(iQ,ffn) @ Wg[:,col / col+1024] + bg).
// ---------------------------------------------------------------------------
__global__ __launch_bounds__(256, 2)
void gemm_gate_kernel(const u16* __restrict__ iQb, const u16* __restrict__ ffn,
                      const u16* __restrict__ Wgt, const float* __restrict__ bg,
                      const float* __restrict__ iQ, float* __restrict__ out,
                      int M, int D2 /*2048*/) {
    __shared__ u16 As [128 * 32];
    __shared__ u16 Bs0[128 * 32];
    __shared__ u16 Bs1[128 * 32];

    const int tid  = threadIdx.x;
    const int m0   = blockIdx.x * 128;
    const int n0   = blockIdx.y * 128;          // out-col tile, n0 < 1024
    const int wave = tid >> 6, lane = tid & 63;
    const int wm   = (wave & 1) << 6;
    const int wn   = (wave >> 1) << 6;
    const int quad = lane >> 4, l16 = lane & 15;
    const int D = D2 >> 1;                      // 1024

    f32x4 acc[2][4][4];
    #pragma unroll
    for (int p = 0; p < 2; ++p)
        #pragma unroll
        for (int i = 0; i < 4; ++i)
            #pragma unroll
            for (int j = 0; j < 4; ++j) acc[p][i][j] = (f32x4){0.f, 0.f, 0.f, 0.f};

    const int o1 = tid * 16, o2 = o1 + 4096;
    const int r1 = o1 >> 6, c1 = o1 & 63;
    const int r2 = o2 >> 6, c2 = o2 & 63;

    const int ktiles = D2 >> 5;                 // 64
    for (int kt = 0; kt < ktiles; ++kt) {
        const int kb = kt << 5;
        const char* Ab = (const char*)((kb < D) ? (iQb + kb) : (ffn + (kb - D)));
        const char* B0 = (const char*)(Wgt + (size_t)n0 * D2 + kb);
        const char* B1 = (const char*)(Wgt + (size_t)(n0 + D) * D2 + kb);
        G2L16(Ab + (size_t)(m0 + r1) * D * 2 + c1, (char*)As + o1);
        G2L16(Ab + (size_t)(m0 + r2) * D * 2 + c2, (char*)As + o2);
        G2L16(B0 + (size_t)r1 * D2 * 2 + c1, (char*)Bs0 + o1);
        G2L16(B0 + (size_t)r2 * D2 * 2 + c2, (char*)Bs0 + o2);
        G2L16(B1 + (size_t)r1 * D2 * 2 + c1, (char*)Bs1 + o1);
        G2L16(B1 + (size_t)r2 * D2 * 2 + c2, (char*)Bs1 + o2);
        __syncthreads();

        short8 af[4], bf0[4], bf1[4];
        #pragma unroll
        for (int mi = 0; mi < 4; ++mi)
            af[mi] = *(const short8*)(As + (wm + mi * 16 + l16) * 32 + quad * 8);
        #pragma unroll
        for (int ni = 0; ni < 4; ++ni) {
            bf0[ni] = *(const short8*)(Bs0 + (wn + ni * 16 + l16) * 32 + quad * 8);
            bf1[ni] = *(const short8*)(Bs1 + (wn + ni * 16 + l16) * 32 + quad * 8);
        }
        #pragma unroll
        for (int mi = 0; mi < 4; ++mi)
            #pragma unroll
            for (int ni = 0; ni < 4; ++ni) {
                acc[0][mi][ni] = __builtin_amdgcn_mfma_f32_16x16x32_bf16(
                    af[mi], bf0[ni], acc[0][mi][ni], 0, 0, 0);
                acc[1][mi][ni] = __builtin_amdgcn_mfma_f32_16x16x32_bf16(
                    af[mi], bf1[ni], acc[1][mi][ni], 0, 0, 0);
            }
        __syncthreads();
    }

    #pragma unroll
    for (int ni = 0; ni < 4; ++ni) {
        const int col = n0 + wn + ni * 16 + l16;
        const float bgi = bg[col];
        const float bgf = bg[col + D];
        #pragma unroll
        for (int mi = 0; mi < 4; ++mi) {
            const int row0 = m0 + wm + mi * 16 + quad * 4;
            #pragma unroll
            for (int r = 0; r < 4; ++r) {
                const size_t idx = (size_t)(row0 + r) * D + col;
                const float gi = 1.0f / (1.0f + __expf(-(acc[0][mi][ni][r] + bgi)));
                const float gf = 1.0f / (1.0f + __expf(-(acc[1][mi][ni][r] + bgf)));
                out[idx] = gi * iQ[idx] + gf * b2f(ffn[idx]);
            }
        }
    }
}

// ---------------------------------------------------------------------------
extern "C" void kernel_launch(void* const* d_in, const int* in_sizes, int n_in,
                              void* d_out, int out_size, void* d_ws, size_t ws_size,
                              hipStream_t stream) {
    const int B = 4, S = 2048, D = 1024, D2 = 2048;
    const int M = B * S;  // 8192

    const float* iQ = (const float*)d_in[0];
    const float* iV = (const float*)d_in[1];
    const float* W1 = (const float*)d_in[2];
    const float* b1 = (const float*)d_in[3];
    const float* W2 = (const float*)d_in[4];
    const float* b2 = (const float*)d_in[5];
    const float* Wg = (const float*)d_in[6];
    const float* bg = (const float*)d_in[7];
    float* out = (float*)d_out;

    // workspace, no aliasing (61 MB):
    u16*   regA = (u16*)d_ws;                    // avg -> ffn   (16 MB)
    u16*   regB = regA + (size_t)M * D;          // h            (16 MB)
    u16*   iQb  = regB + (size_t)M * D;          // iQ bf16      (16 MB)
    u16*   W1t  = iQb  + (size_t)M * D;          //              ( 2 MB)
    u16*   W2t  = W1t  + (size_t)D * D;          //              ( 2 MB)
    u16*   Wgt  = W2t  + (size_t)D * D;          //              ( 8 MB)
    float* csum = (float*)(Wgt + (size_t)D2 * D2); // B*64*D f32 ( 1 MB)

    u16* avg = regA;
    u16* ffn = regA;
    u16* h   = regB;

    // 1. all independent prologue work in one big dispatch (14592 blocks)
    prologue_kernel<<<14592, 256, 0, stream>>>(W1, W1t, W2, W2t, Wg, Wgt,
                                               iQ, iQb, iV, csum);
    // 2. causal cumulative mean
    scan_kernel<<<B * 64, 256, 0, stream>>>(iV, csum, avg);
    // 3. h = relu(avg @ W1 + b1)
    gemm_kernel<0><<<dim3(M / 128, D / 128), 256, 0, stream>>>(avg, W1t, b1, h, M, D, D);
    // 4. ffn = h @ W2 + b2   (overlays avg)
    gemm_kernel<1><<<dim3(M / 128, D / 128), 256, 0, stream>>>(h, W2t, b2, ffn, M, D, D);
    // 5. fused gate GEMM + epilogue
    gemm_gate_kernel<<<dim3(M / 128, D / 128), 256, 0, stream>>>(
        iQb, ffn, Wgt, bg, iQ, out, M, D2);
}

// Round 4
// 267.798 us; speedup vs baseline: 1.4118x; 1.1364x over previous
//
#include <hip/hip_runtime.h>
#include <hip/hip_bf16.h>
#include <cstdint>

typedef unsigned short u16;
typedef unsigned int   u32;

typedef __attribute__((ext_vector_type(8))) short short8;   // 8 x bf16 (4 VGPRs)
typedef __attribute__((ext_vector_type(4))) float f32x4;    // MFMA accumulator

__device__ __forceinline__ float b2f(u16 v) { return __uint_as_float(((u32)v) << 16); }
__device__ __forceinline__ u16 f2b(float f) {
    u32 u = __float_as_uint(f);
    u += 0x7FFFu + ((u >> 16) & 1u);   // round-to-nearest-even
    return (u16)(u >> 16);
}

#define G2L16(gp, lp) __builtin_amdgcn_global_load_lds(                       \
    (const __attribute__((address_space(1))) void*)(gp),                      \
    (__attribute__((address_space(3))) void*)(lp), 16, 0, 0)

// ---------------------------------------------------------------------------
// Fused prologue (all independent work, one dispatch):
//   blocks [0,1024)      : W1 (1024x1024 f32) -> W1t (bf16, transposed)
//   blocks [1024,2048)   : W2 -> W2t
//   blocks [2048,6144)   : Wg (2048x2048) -> Wgt
//   blocks [6144,14336)  : cast iQ f32 -> iQb bf16
//   blocks [14336,14592) : chunk sums of iV (64 chunks of 32 rows per batch)
// ---------------------------------------------------------------------------
__device__ __forceinline__ void transpose_body(const float* __restrict__ in,
                                               u16* __restrict__ out,
                                               int R, int C, int lb, int tilesX,
                                               float (*tile)[33]) {
    const int bx = (lb % tilesX) * 32;
    const int by = (lb / tilesX) * 32;
    const int tx = threadIdx.x & 31, ty = threadIdx.x >> 5;   // 32 x 8
    #pragma unroll
    for (int i = 0; i < 32; i += 8)
        tile[ty + i][tx] = in[(size_t)(by + ty + i) * C + (bx + tx)];
    __syncthreads();
    #pragma unroll
    for (int i = 0; i < 32; i += 8)
        out[(size_t)(bx + ty + i) * R + (by + tx)] = f2b(tile[tx][ty + i]);
}

__global__ void prologue_kernel(const float* __restrict__ W1, u16* __restrict__ W1t,
                                const float* __restrict__ W2, u16* __restrict__ W2t,
                                const float* __restrict__ Wg, u16* __restrict__ Wgt,
                                const float* __restrict__ iQ, u16* __restrict__ iQb,
                                const float* __restrict__ iV, float* __restrict__ csum) {
    __shared__ float tile[32][33];
    const int bid = blockIdx.x;
    const int tid = threadIdx.x;
    if (bid < 1024) {
        transpose_body(W1, W1t, 1024, 1024, bid, 32, tile);
    } else if (bid < 2048) {
        transpose_body(W2, W2t, 1024, 1024, bid - 1024, 32, tile);
    } else if (bid < 6144) {
        transpose_body(Wg, Wgt, 2048, 2048, bid - 2048, 64, tile);
    } else if (bid < 14336) {
        const size_t i = ((size_t)(bid - 6144) * 256 + tid) * 4;
        const float4 v = *(const float4*)(iQ + i);
        ushort4 o;
        o.x = f2b(v.x); o.y = f2b(v.y); o.z = f2b(v.z); o.w = f2b(v.w);
        *(ushort4*)(iQb + i) = o;
    } else {
        // chunk sums: 32-row chunks, 64 chunks per batch, 4 batches -> 256 blocks
        const int idx = bid - 14336;
        const int b = idx >> 6, c = idx & 63;
        const int d = tid * 4;                              // D = 1024
        const float* src = iV + ((size_t)(b * 2048 + c * 32)) * 1024 + d;
        float4 s = {0.f, 0.f, 0.f, 0.f};
        #pragma unroll 8
        for (int i = 0; i < 32; ++i) {
            const float4 v = *(const float4*)(src + (size_t)i * 1024);
            s.x += v.x; s.y += v.y; s.z += v.z; s.w += v.w;
        }
        *(float4*)(csum + ((size_t)(b * 64 + c)) * 1024 + d) = s;
    }
}

// ---------------------------------------------------------------------------
// Scan: prefix over chunk sums (4-way ILP) + in-chunk serial scan -> avg (bf16).
// ---------------------------------------------------------------------------
__global__ void scan_kernel(const float* __restrict__ iV, const float* __restrict__ csum,
                            u16* __restrict__ avg) {
    const int c = blockIdx.x & 63, b = blockIdx.x >> 6;
    const int d = threadIdx.x * 4;
    const float* cs = csum + (size_t)b * 64 * 1024 + d;
    float4 a0 = {0,0,0,0}, a1 = {0,0,0,0}, a2 = {0,0,0,0}, a3 = {0,0,0,0};
    int cc = 0;
    for (; cc + 4 <= c; cc += 4) {
        const float4 v0 = *(const float4*)(cs + (size_t)(cc + 0) * 1024);
        const float4 v1 = *(const float4*)(cs + (size_t)(cc + 1) * 1024);
        const float4 v2 = *(const float4*)(cs + (size_t)(cc + 2) * 1024);
        const float4 v3 = *(const float4*)(cs + (size_t)(cc + 3) * 1024);
        a0.x += v0.x; a0.y += v0.y; a0.z += v0.z; a0.w += v0.w;
        a1.x += v1.x; a1.y += v1.y; a1.z += v1.z; a1.w += v1.w;
        a2.x += v2.x; a2.y += v2.y; a2.z += v2.z; a2.w += v2.w;
        a3.x += v3.x; a3.y += v3.y; a3.z += v3.z; a3.w += v3.w;
    }
    for (; cc < c; ++cc) {
        const float4 v = *(const float4*)(cs + (size_t)cc * 1024);
        a0.x += v.x; a0.y += v.y; a0.z += v.z; a0.w += v.w;
    }
    float4 acc;
    acc.x = (a0.x + a1.x) + (a2.x + a3.x);
    acc.y = (a0.y + a1.y) + (a2.y + a3.y);
    acc.z = (a0.z + a1.z) + (a2.z + a3.z);
    acc.w = (a0.w + a1.w) + (a2.w + a3.w);

    const size_t off = ((size_t)(b * 2048 + c * 32)) * 1024 + d;
    const float* src = iV + off;
    u16*         dst = avg + off;
    const int s0 = c * 32;
    #pragma unroll 4
    for (int i = 0; i < 32; ++i) {
        const float4 v = *(const float4*)(src + (size_t)i * 1024);
        acc.x += v.x; acc.y += v.y; acc.z += v.z; acc.w += v.w;
        const float inv = 1.0f / (float)(s0 + i + 1);
        ushort4 o;
        o.x = f2b(acc.x * inv); o.y = f2b(acc.y * inv);
        o.z = f2b(acc.z * inv); o.w = f2b(acc.w * inv);
        *(ushort4*)(dst + (size_t)i * 1024) = o;
    }
}

// ---------------------------------------------------------------------------
// MFMA GEMM, BK=64, XOR-swizzled LDS (conflict-free ds_read_b128).
// LDS row = 128B (8 chunks of 16B). Chunk q of row r lives at slot q^(r&7).
// Staging lane with slot s fetches global chunk s^(r&7); fragment reads use
// slot (h*4+quad)^(R&7). Bank = 4*(q^(r&7)) -> 2 lanes/bank (free).
// EPI: 0 = relu(x+b), 1 = x+b.
// ---------------------------------------------------------------------------
template <int EPI>
__global__ __launch_bounds__(256, 2)
void gemm_kernel(const u16* __restrict__ A, const u16* __restrict__ Bt,
                 const float* __restrict__ bias, u16* __restrict__ C,
                 int M, int N, int K) {
    __shared__ u16 As[128 * 64];
    __shared__ u16 Bs[128 * 64];

    const int tid  = threadIdx.x;
    const int m0   = blockIdx.x * 128;
    const int n0   = blockIdx.y * 128;
    const int wave = tid >> 6, lane = tid & 63;
    const int wm   = (wave & 1) << 6;
    const int wn   = (wave >> 1) << 6;
    const int quad = lane >> 4, l16 = lane & 15;

    f32x4 acc[4][4];
    #pragma unroll
    for (int i = 0; i < 4; ++i)
        #pragma unroll
        for (int j = 0; j < 4; ++j) acc[i][j] = (f32x4){0.f, 0.f, 0.f, 0.f};

    // staging: 4 issues of 4KB each per tile
    int oo[4], rr[4], qq[4];
    #pragma unroll
    for (int j = 0; j < 4; ++j) {
        oo[j] = tid * 16 + j * 4096;
        rr[j] = oo[j] >> 7;
        qq[j] = ((oo[j] >> 4) & 7) ^ (rr[j] & 7);
    }

    const int ktiles = K >> 6;
    for (int kt = 0; kt < ktiles; ++kt) {
        const int kb = kt << 6;
        #pragma unroll
        for (int j = 0; j < 4; ++j) {
            G2L16((const char*)A  + ((size_t)(m0 + rr[j]) * K + kb) * 2 + qq[j] * 16,
                  (char*)As + oo[j]);
            G2L16((const char*)Bt + ((size_t)(n0 + rr[j]) * K + kb) * 2 + qq[j] * 16,
                  (char*)Bs + oo[j]);
        }
        __syncthreads();

        #pragma unroll
        for (int h = 0; h < 2; ++h) {
            short8 af[4], bf[4];
            #pragma unroll
            for (int mi = 0; mi < 4; ++mi) {
                const int R = wm + mi * 16 + l16;
                af[mi] = *(const short8*)(As + R * 64 + ((((h << 2) | quad) ^ (R & 7)) << 3));
            }
            #pragma unroll
            for (int ni = 0; ni < 4; ++ni) {
                const int R = wn + ni * 16 + l16;
                bf[ni] = *(const short8*)(Bs + R * 64 + ((((h << 2) | quad) ^ (R & 7)) << 3));
            }
            #pragma unroll
            for (int mi = 0; mi < 4; ++mi)
                #pragma unroll
                for (int ni = 0; ni < 4; ++ni)
                    acc[mi][ni] = __builtin_amdgcn_mfma_f32_16x16x32_bf16(
                        af[mi], bf[ni], acc[mi][ni], 0, 0, 0);
        }
        __syncthreads();
    }

    #pragma unroll
    for (int ni = 0; ni < 4; ++ni) {
        const int col = n0 + wn + ni * 16 + l16;
        const float bv = bias[col];
        #pragma unroll
        for (int mi = 0; mi < 4; ++mi) {
            const int row0 = m0 + wm + mi * 16 + quad * 4;
            #pragma unroll
            for (int r = 0; r < 4; ++r) {
                float v = acc[mi][ni][r] + bv;
                if (EPI == 0) v = fmaxf(v, 0.f);
                C[(size_t)(row0 + r) * N + col] = f2b(v);
            }
        }
    }
}

// ---------------------------------------------------------------------------
// Fused GEMM3 + sigmoid + gate, BK=64 + swizzled LDS.
// out = gi*iQ + gf*ffn (f32), gi/gf = sigmoid(concat(iQ,ffn)@Wg[:,col/col+D]+bg)
// ---------------------------------------------------------------------------
__global__ __launch_bounds__(256, 2)
void gemm_gate_kernel(const u16* __restrict__ iQb, const u16* __restrict__ ffn,
                      const u16* __restrict__ Wgt, const float* __restrict__ bg,
                      const float* __restrict__ iQ, float* __restrict__ out,
                      int M, int D2 /*2048*/) {
    __shared__ u16 As [128 * 64];
    __shared__ u16 Bs0[128 * 64];
    __shared__ u16 Bs1[128 * 64];

    const int tid  = threadIdx.x;
    const int m0   = blockIdx.x * 128;
    const int n0   = blockIdx.y * 128;          // out-col tile, n0 < 1024
    const int wave = tid >> 6, lane = tid & 63;
    const int wm   = (wave & 1) << 6;
    const int wn   = (wave >> 1) << 6;
    const int quad = lane >> 4, l16 = lane & 15;
    const int D = D2 >> 1;                      // 1024

    f32x4 acc[2][4][4];
    #pragma unroll
    for (int p = 0; p < 2; ++p)
        #pragma unroll
        for (int i = 0; i < 4; ++i)
            #pragma unroll
            for (int j = 0; j < 4; ++j) acc[p][i][j] = (f32x4){0.f, 0.f, 0.f, 0.f};

    int oo[4], rr[4], qq[4];
    #pragma unroll
    for (int j = 0; j < 4; ++j) {
        oo[j] = tid * 16 + j * 4096;
        rr[j] = oo[j] >> 7;
        qq[j] = ((oo[j] >> 4) & 7) ^ (rr[j] & 7);
    }

    const int ktiles = D2 >> 6;                 // 32
    for (int kt = 0; kt < ktiles; ++kt) {
        const int kb = kt << 6;
        const char* Ab = (const char*)((kb < D) ? (iQb + kb) : (ffn + (kb - D)));
        const char* B0 = (const char*)(Wgt + (size_t)n0 * D2 + kb);
        const char* B1 = (const char*)(Wgt + (size_t)(n0 + D) * D2 + kb);
        #pragma unroll
        for (int j = 0; j < 4; ++j) {
            G2L16(Ab + (size_t)(m0 + rr[j]) * D * 2 + qq[j] * 16, (char*)As  + oo[j]);
            G2L16(B0 + (size_t)rr[j] * D2 * 2 + qq[j] * 16,       (char*)Bs0 + oo[j]);
            G2L16(B1 + (size_t)rr[j] * D2 * 2 + qq[j] * 16,       (char*)Bs1 + oo[j]);
        }
        __syncthreads();

        #pragma unroll
        for (int h = 0; h < 2; ++h) {
            short8 af[4], bf0[4], bf1[4];
            #pragma unroll
            for (int mi = 0; mi < 4; ++mi) {
                const int R = wm + mi * 16 + l16;
                af[mi] = *(const short8*)(As + R * 64 + ((((h << 2) | quad) ^ (R & 7)) << 3));
            }
            #pragma unroll
            for (int ni = 0; ni < 4; ++ni) {
                const int R = wn + ni * 16 + l16;
                const int so = R * 64 + ((((h << 2) | quad) ^ (R & 7)) << 3);
                bf0[ni] = *(const short8*)(Bs0 + so);
                bf1[ni] = *(const short8*)(Bs1 + so);
            }
            #pragma unroll
            for (int mi = 0; mi < 4; ++mi)
                #pragma unroll
                for (int ni = 0; ni < 4; ++ni) {
                    acc[0][mi][ni] = __builtin_amdgcn_mfma_f32_16x16x32_bf16(
                        af[mi], bf0[ni], acc[0][mi][ni], 0, 0, 0);
                    acc[1][mi][ni] = __builtin_amdgcn_mfma_f32_16x16x32_bf16(
                        af[mi], bf1[ni], acc[1][mi][ni], 0, 0, 0);
                }
        }
        __syncthreads();
    }

    #pragma unroll
    for (int ni = 0; ni < 4; ++ni) {
        const int col = n0 + wn + ni * 16 + l16;
        const float bgi = bg[col];
        const float bgf = bg[col + D];
        #pragma unroll
        for (int mi = 0; mi < 4; ++mi) {
            const int row0 = m0 + wm + mi * 16 + quad * 4;
            #pragma unroll
            for (int r = 0; r < 4; ++r) {
                const size_t idx = (size_t)(row0 + r) * D + col;
                const float gi = 1.0f / (1.0f + __expf(-(acc[0][mi][ni][r] + bgi)));
                const float gf = 1.0f / (1.0f + __expf(-(acc[1][mi][ni][r] + bgf)));
                out[idx] = gi * iQ[idx] + gf * b2f(ffn[idx]);
            }
        }
    }
}

// ---------------------------------------------------------------------------
extern "C" void kernel_launch(void* const* d_in, const int* in_sizes, int n_in,
                              void* d_out, int out_size, void* d_ws, size_t ws_size,
                              hipStream_t stream) {
    const int B = 4, S = 2048, D = 1024, D2 = 2048;
    const int M = B * S;  // 8192

    const float* iQ = (const float*)d_in[0];
    const float* iV = (const float*)d_in[1];
    const float* W1 = (const float*)d_in[2];
    const float* b1 = (const float*)d_in[3];
    const float* W2 = (const float*)d_in[4];
    const float* b2 = (const float*)d_in[5];
    const float* Wg = (const float*)d_in[6];
    const float* bg = (const float*)d_in[7];
    float* out = (float*)d_out;

    // workspace, no aliasing (61 MB):
    u16*   regA = (u16*)d_ws;                    // avg -> ffn   (16 MB)
    u16*   regB = regA + (size_t)M * D;          // h            (16 MB)
    u16*   iQb  = regB + (size_t)M * D;          // iQ bf16      (16 MB)
    u16*   W1t  = iQb  + (size_t)M * D;          //              ( 2 MB)
    u16*   W2t  = W1t  + (size_t)D * D;          //              ( 2 MB)
    u16*   Wgt  = W2t  + (size_t)D * D;          //              ( 8 MB)
    float* csum = (float*)(Wgt + (size_t)D2 * D2); // B*64*D f32 ( 1 MB)

    u16* avg = regA;
    u16* ffn = regA;
    u16* h   = regB;

    // 1. all independent prologue work in one big dispatch (14592 blocks)
    prologue_kernel<<<14592, 256, 0, stream>>>(W1, W1t, W2, W2t, Wg, Wgt,
                                               iQ, iQb, iV, csum);
    // 2. causal cumulative mean
    scan_kernel<<<B * 64, 256, 0, stream>>>(iV, csum, avg);
    // 3. h = relu(avg @ W1 + b1)
    gemm_kernel<0><<<dim3(M / 128, D / 128), 256, 0, stream>>>(avg, W1t, b1, h, M, D, D);
    // 4. ffn = h @ W2 + b2   (overlays avg)
    gemm_kernel<1><<<dim3(M / 128, D / 128), 256, 0, stream>>>(h, W2t, b2, ffn, M, D, D);
    // 5. fused gate GEMM + epilogue
    gemm_gate_kernel<<<dim3(M / 128, D / 128), 256, 0, stream>>>(
        iQb, ffn, Wgt, bg, iQ, out, M, D2);
}